// Round 15
// baseline (33.008 us; speedup 1.0000x reference)
//
#include <hip/hip_runtime.h>
#include <math.h>

#define NN 16
#define GG 4096
#define STR 76            // feature-vector stride (floats)
#define SSTR 68           // sigma stage stride (floats)
#define NWG GG            // 4096 blocks, 1 wave per block, 1 grid point per wave

#define LN2 0.6931471805599453f

__device__ __forceinline__ float frcp(float x) { return __builtin_amdgcn_rcpf(x); }
__device__ __forceinline__ float flogabs(float x) {
    return __builtin_amdgcn_logf(fabsf(x)) * LN2;
}

// ---- DPP helpers (quad_perm = VALU cross-lane, no DS pipe) ----
template <int CTRL>
__device__ __forceinline__ float dppf(float x) {
    return __builtin_bit_cast(float, __builtin_amdgcn_mov_dpp(
        __builtin_bit_cast(int, x), CTRL, 0xF, 0xF, true));
}
__device__ __forceinline__ float qb(float x, int L) {
    switch (L) {
        case 0:  return dppf<0x00>(x);
        case 1:  return dppf<0x55>(x);
        case 2:  return dppf<0xAA>(x);
        default: return dppf<0xFF>(x);
    }
}
__device__ __forceinline__ float qsum(float x) {
    x += dppf<0xB1>(x);  // perm[1,0,3,2]
    x += dppf<0x4E>(x);  // perm[2,3,0,1]
    return x;
}
__device__ __forceinline__ void bcast_row(float out[8], const float r0[8],
                                          const float r1[8], int k) {
#pragma unroll
    for (int c = 0; c < 8; ++c) {
        float s = (k < 4) ? r0[c] : r1[c];
        out[c] = qb(s, k & 3);
    }
}
__device__ __forceinline__ float sel_lo(const float r[8], int q) {
    return (q == 0) ? r[0] : (q == 1) ? r[1] : (q == 2) ? r[2] : r[3];
}
__device__ __forceinline__ float sel_hi(const float r[8], int q) {
    return (q == 0) ? r[4] : (q == 1) ? r[5] : (q == 2) ? r[6] : r[7];
}
__device__ __forceinline__ void ld_row(float r[8], const float* p) {
    float4 x = *(const float4*)p, y = *(const float4*)(p + 4);
    r[0] = x.x; r[1] = x.y; r[2] = x.z; r[3] = x.w;
    r[4] = y.x; r[5] = y.y; r[6] = y.z; r[7] = y.w;
}
__device__ __forceinline__ void st_row(float* p, const float r[8]) {
    *(float4*)p       = make_float4(r[0], r[1], r[2], r[3]);
    *(float4*)(p + 4) = make_float4(r[4], r[5], r[6], r[7]);
}
__device__ __forceinline__ float dot8(const float a[8], const float b[8]) {
    float s = a[0] * b[0];
    s = fmaf(a[1], b[1], s); s = fmaf(a[2], b[2], s);
    s = fmaf(a[3], b[3], s); s = fmaf(a[4], b[4], s);
    s = fmaf(a[5], b[5], s); s = fmaf(a[6], b[6], s);
    s = fmaf(a[7], b[7], s);
    return s;
}

// Fused 3-matrix elimination: full GJ inverse of T and S, LU det of V,
// interleaved so the three serial broadcast->rcp->update chains overlap.
// Lane q holds rows q (x0) and q+4 (x1) of each matrix. No pivoting.
__device__ __forceinline__ void elim3(float t0[8], float t1[8],
                                      float s0[8], float s1[8],
                                      float v0[8], float v1[8],
                                      float& ppT, float& ppS, float& ppV,
                                      int q) {
    ppT = 1.f; ppS = 1.f; ppV = 1.f;
#pragma unroll
    for (int k = 0; k < 8; ++k) {
        float Tk[8], Sk[8], Vk[8];
        bcast_row(Tk, t0, t1, k);
        bcast_row(Sk, s0, s1, k);
#pragma unroll
        for (int c = k; c < 8; ++c) {          // V: only cols >= k needed
            float sv = (k < 4) ? v0[c] : v1[c];
            Vk[c] = qb(sv, k & 3);
        }
        float pT = Tk[k], pS = Sk[k], pV = Vk[k];
        ppT *= pT; ppS *= pS; ppV *= pV;
        float iT = frcp(pT), iS = frcp(pS), iV = frcp(pV);
        const bool own0 = (k < 4) && (q == k);
        const bool own1 = (k >= 4) && (q == k - 4);
        float mT0 = -(own0 ? -1.0f : t0[k]) * iT;
        float mT1 = -(own1 ? -1.0f : t1[k]) * iT;
        float mS0 = -(own0 ? -1.0f : s0[k]) * iS;
        float mS1 = -(own1 ? -1.0f : s1[k]) * iS;
        float fV0 = (q > k) ? v0[k] * iV : 0.f;
        float fV1 = (q + 4 > k) ? v1[k] * iV : 0.f;
#pragma unroll
        for (int c = 0; c < 8; ++c) {
            float bT0 = own0 ? 0.0f : t0[c];
            float bT1 = own1 ? 0.0f : t1[c];
            t0[c] = fmaf(mT0, Tk[c], bT0);
            t1[c] = fmaf(mT1, Tk[c], bT1);
            float bS0 = own0 ? 0.0f : s0[c];
            float bS1 = own1 ? 0.0f : s1[c];
            s0[c] = fmaf(mS0, Sk[c], bS0);
            s1[c] = fmaf(mS1, Sk[c], bS1);
        }
        t0[k] = mT0; t1[k] = mT1;
        s0[k] = mS0; s1[k] = mS1;
#pragma unroll
        for (int c = k + 1; c < 8; ++c) {
            v0[c] = fmaf(-fV0, Vk[c], v0[c]);
            v1[c] = fmaf(-fV1, Vk[c], v1[c]);
        }
    }
}

__global__ __launch_bounds__(64) void pairkl_kernel(
    const float* __restrict__ omega, const float* __restrict__ links,
    const float* __restrict__ mu, const float* __restrict__ sigma,
    float* __restrict__ out) {
    __shared__ __align__(16) float sh_x[NN][STR];
    __shared__ __align__(16) float sh_y[NN][STR];
    // sigma stage overlaid on sh_y (15*68+64 = 1084 <= 1216 floats): every
    // sh_s read precedes every sh_y write in the single wave's program order,
    // and sh_s aliases sh_y so the compiler cannot reorder them.
    float* sh_s = &sh_y[0][0];  // layout [item][SSTR]

    const int bid  = blockIdx.x;
    const int g    = (bid & 7) * (NWG / 8) + (bid >> 3);  // XCD-bijective swizzle
    const int lane = threadIdx.x;
    const int item = lane >> 2;
    const int q    = lane & 3;
    const int mb   = (item * GG + g) * 64;

    // ---- Load burst: everything issued up front so latency rides under
    //      T + elim3 + streams. omega COLUMNS (for P) hoisted here. ----
    float v0[8], v1[8], o0[8], o1[8], s0[8], s1[8], mq[8];
    float oc0[8], oc1[8];
    {
        const float* l0p = links + ((item * 2 + 0) * GG + g) * 64;
        const float* l1p = links + ((item * 2 + 1) * GG + g) * 64;
        float la[8], lb[8];
        ld_row(la, l0p + q * 8);
        ld_row(lb, l1p + q * 8);
#pragma unroll
        for (int c = 0; c < 8; ++c) v0[c] = la[c] + lb[c] - ((c == q) ? 1.f : 0.f);
        ld_row(la, l0p + (q + 4) * 8);
        ld_row(lb, l1p + (q + 4) * 8);
#pragma unroll
        for (int c = 0; c < 8; ++c) v1[c] = la[c] + lb[c] - ((c == q + 4) ? 1.f : 0.f);
    }
    ld_row(o0, omega + mb + q * 8);
    ld_row(o1, omega + mb + (q + 4) * 8);
    ld_row(s0, sigma + mb + q * 8);
    ld_row(s1, sigma + mb + (q + 4) * 8);
#pragma unroll
    for (int a = 0; a < 8; ++a) {
        oc0[a] = omega[mb + a * 8 + q];
        oc1[a] = omega[mb + a * 8 + q + 4];
    }
    st_row(&sh_s[item * SSTR + q * 8], s0);
    st_row(&sh_s[item * SSTR + (q + 4) * 8], s1);
    ld_row(mq, mu + (item * GG + g) * 8);

    // ---- T = omega @ V ----
    float R0[8], R1[8];
#pragma unroll
    for (int c = 0; c < 8; ++c) { R0[c] = 0.f; R1[c] = 0.f; }
#pragma unroll
    for (int b = 0; b < 8; ++b) {
        float Vb[8]; bcast_row(Vb, v0, v1, b);
#pragma unroll
        for (int c = 0; c < 8; ++c) {
            R0[c] = fmaf(o0[b], Vb[c], R0[c]);
            R1[c] = fmaf(o1[b], Vb[c], R1[c]);
        }
    }

    // ---- Fused eliminations (serial-latency critical): boost wave prio ----
    __builtin_amdgcn_s_setprio(1);
    float ppT, ppS, ppV;
    elim3(R0, R1, s0, s1, v0, v1, ppT, ppS, ppV, q);
    float ldT = flogabs(ppT);
    float ld1 = flogabs(ppS);
    float ldV = flogabs(ppV);
    __builtin_amdgcn_s_setprio(0);

    // ---- Fused streams: Z = Winv @ sigma (LDS) || U = siginv @ omega (DPP) ----
    float Z0[8], Z1[8], U0[8], U1[8];
#pragma unroll
    for (int c = 0; c < 8; ++c) { Z0[c] = 0.f; Z1[c] = 0.f; U0[c] = 0.f; U1[c] = 0.f; }
#pragma unroll
    for (int b = 0; b < 8; ++b) {
        float sr[8]; ld_row(sr, &sh_s[item * SSTR + b * 8]);   // original sigma
        float Ob[8]; bcast_row(Ob, o0, o1, b);
#pragma unroll
        for (int c = 0; c < 8; ++c) {
            Z0[c] = fmaf(R0[b], sr[c], Z0[c]);
            Z1[c] = fmaf(R1[b], sr[c], Z1[c]);
            U0[c] = fmaf(s0[b], Ob[c], U0[c]);
            U1[c] = fmaf(s1[b], Ob[c], U1[c]);
        }
    }

    float u_lo = dot8(R0, mq), u_hi = dot8(R1, mq);
    float uf[8];
#pragma unroll
    for (int c = 0; c < 4; ++c) { uf[c] = qb(u_lo, c); uf[c + 4] = qb(u_hi, c); }
    float mql = sel_lo(mq, q), mqh = sel_hi(mq, q);
    float cc  = qsum(dot8(s0, mq) * mql + dot8(s1, mq) * mqh);
    float wf[8];
#pragma unroll
    for (int c = 0; c < 8; ++c) wf[c] = qsum(fmaf(mql, U0[c], mqh * U1[c]));

    // ---- X = Z Winv^T + u u^T  (reuse v regs) ----
#pragma unroll
    for (int c = 0; c < 8; ++c) {
        float Wc[8]; bcast_row(Wc, R0, R1, c);
        v0[c] = fmaf(u_lo, uf[c], dot8(Z0, Wc));
        v1[c] = fmaf(u_hi, uf[c], dot8(Z1, Wc));
    }
    st_row(&sh_x[item][q * 8], v0);
    st_row(&sh_x[item][(q + 4) * 8], v1);

    // ---- P = omega^T U  (columns preloaded; reuse s regs) ----
#pragma unroll
    for (int c = 0; c < 8; ++c) { s0[c] = 0.f; s1[c] = 0.f; }
#pragma unroll
    for (int a = 0; a < 8; ++a) {
        float Ua[8]; bcast_row(Ua, U0, U1, a);
#pragma unroll
        for (int c = 0; c < 8; ++c) {
            s0[c] = fmaf(oc0[a], Ua[c], s0[c]);
            s1[c] = fmaf(oc1[a], Ua[c], s1[c]);
        }
    }
    st_row(&sh_y[item][q * 8], s0);   // after this, sh_s region may be clobbered
    st_row(&sh_y[item][(q + 4) * 8], s1);

    if (q == 0) {
        float ldo = ldT - ldV;
        float a_i = 2.f * ldT - ld1;
        float s_j = ld1 - 2.f * ldo + cc - 8.0f;
        *(float4*)&sh_x[item][64] = make_float4(uf[0], uf[1], uf[2], uf[3]);
        *(float4*)&sh_x[item][68] = make_float4(uf[4], uf[5], uf[6], uf[7]);
        *(float4*)&sh_x[item][72] = make_float4(a_i, 1.f, 0.f, 0.f);
        *(float4*)&sh_y[item][64] =
            make_float4(-2.f * wf[0], -2.f * wf[1], -2.f * wf[2], -2.f * wf[3]);
        *(float4*)&sh_y[item][68] =
            make_float4(-2.f * wf[4], -2.f * wf[5], -2.f * wf[6], -2.f * wf[7]);
        *(float4*)&sh_y[item][72] = make_float4(1.f, s_j, 0.f, 0.f);
    }
    // single-wave workgroup: DS ops complete in program order; compiler
    // inserts lgkmcnt for RAW. Fence stops compile-time reordering.
    asm volatile("" ::: "memory");

    // ---- Phase 2: E[i,j] = 0.5 * dot76(x_i, y_j); 2i x 2j per lane ----
    {
        const int i0 = lane >> 3, j0 = lane & 7;
        const int i1 = i0 + 8, j1 = j0 + 8;
        const float4* x0 = (const float4*)&sh_x[i0][0];
        const float4* x1 = (const float4*)&sh_x[i1][0];
        const float4* y0 = (const float4*)&sh_y[j0][0];
        const float4* y1 = (const float4*)&sh_y[j1][0];
        float d00 = 0.f, d01 = 0.f, d10 = 0.f, d11 = 0.f;
#pragma unroll
        for (int k = 0; k < STR / 4; ++k) {
            float4 a0 = x0[k], a1 = x1[k], b0 = y0[k], b1 = y1[k];
            d00 = fmaf(a0.x, b0.x, d00); d00 = fmaf(a0.y, b0.y, d00);
            d00 = fmaf(a0.z, b0.z, d00); d00 = fmaf(a0.w, b0.w, d00);
            d01 = fmaf(a0.x, b1.x, d01); d01 = fmaf(a0.y, b1.y, d01);
            d01 = fmaf(a0.z, b1.z, d01); d01 = fmaf(a0.w, b1.w, d01);
            d10 = fmaf(a1.x, b0.x, d10); d10 = fmaf(a1.y, b0.y, d10);
            d10 = fmaf(a1.z, b0.z, d10); d10 = fmaf(a1.w, b0.w, d10);
            d11 = fmaf(a1.x, b1.x, d11); d11 = fmaf(a1.y, b1.y, d11);
            d11 = fmaf(a1.z, b1.z, d11); d11 = fmaf(a1.w, b1.w, d11);
        }
        const bool dg = (i0 == j0);
        out[(i0 * NN + j0) * GG + g] = dg ? 0.f : 0.5f * d00;
        out[(i0 * NN + j1) * GG + g] = 0.5f * d01;
        out[(i1 * NN + j0) * GG + g] = 0.5f * d10;
        out[(i1 * NN + j1) * GG + g] = dg ? 0.f : 0.5f * d11;
    }
}

extern "C" void kernel_launch(void* const* d_in, const int* in_sizes, int n_in,
                              void* d_out, int out_size, void* d_ws, size_t ws_size,
                              hipStream_t stream) {
    const float* omega = (const float*)d_in[0];
    const float* links = (const float*)d_in[1];
    const float* mu    = (const float*)d_in[2];
    const float* sigma = (const float*)d_in[3];
    float* out = (float*)d_out;
    hipLaunchKernelGGL(pairkl_kernel, dim3(NWG), dim3(64), 0, stream,
                       omega, links, mu, sigma, out);
}

// Round 16
// 26.743 us; speedup vs baseline: 1.2343x; 1.2343x over previous
//
#include <hip/hip_runtime.h>
#include <math.h>

#define NN 16
#define GG 4096
#define STR 76            // feature-vector stride (floats)
#define SSTR 68           // sigma stage stride (floats)
#define NWG GG            // 4096 blocks, 1 wave per block, 1 grid point per wave

#define LN2 0.6931471805599453f

__device__ __forceinline__ float frcp(float x) { return __builtin_amdgcn_rcpf(x); }
__device__ __forceinline__ float flogabs(float x) {
    return __builtin_amdgcn_logf(fabsf(x)) * LN2;
}

// ---- DPP helpers (quad_perm = VALU cross-lane, no DS pipe) ----
template <int CTRL>
__device__ __forceinline__ float dppf(float x) {
    return __builtin_bit_cast(float, __builtin_amdgcn_mov_dpp(
        __builtin_bit_cast(int, x), CTRL, 0xF, 0xF, true));
}
__device__ __forceinline__ float qb(float x, int L) {
    switch (L) {
        case 0:  return dppf<0x00>(x);
        case 1:  return dppf<0x55>(x);
        case 2:  return dppf<0xAA>(x);
        default: return dppf<0xFF>(x);
    }
}
__device__ __forceinline__ float qsum(float x) {
    x += dppf<0xB1>(x);  // perm[1,0,3,2]
    x += dppf<0x4E>(x);  // perm[2,3,0,1]
    return x;
}
__device__ __forceinline__ void bcast_row(float out[8], const float r0[8],
                                          const float r1[8], int k) {
#pragma unroll
    for (int c = 0; c < 8; ++c) {
        float s = (k < 4) ? r0[c] : r1[c];
        out[c] = qb(s, k & 3);
    }
}
__device__ __forceinline__ float sel_lo(const float r[8], int q) {
    return (q == 0) ? r[0] : (q == 1) ? r[1] : (q == 2) ? r[2] : r[3];
}
__device__ __forceinline__ float sel_hi(const float r[8], int q) {
    return (q == 0) ? r[4] : (q == 1) ? r[5] : (q == 2) ? r[6] : r[7];
}
__device__ __forceinline__ void ld_row(float r[8], const float* p) {
    float4 x = *(const float4*)p, y = *(const float4*)(p + 4);
    r[0] = x.x; r[1] = x.y; r[2] = x.z; r[3] = x.w;
    r[4] = y.x; r[5] = y.y; r[6] = y.z; r[7] = y.w;
}
__device__ __forceinline__ void st_row(float* p, const float r[8]) {
    *(float4*)p       = make_float4(r[0], r[1], r[2], r[3]);
    *(float4*)(p + 4) = make_float4(r[4], r[5], r[6], r[7]);
}
__device__ __forceinline__ float dot8(const float a[8], const float b[8]) {
    float s = a[0] * b[0];
    s = fmaf(a[1], b[1], s); s = fmaf(a[2], b[2], s);
    s = fmaf(a[3], b[3], s); s = fmaf(a[4], b[4], s);
    s = fmaf(a[5], b[5], s); s = fmaf(a[6], b[6], s);
    s = fmaf(a[7], b[7], s);
    return s;
}

// Fused 3-matrix elimination: full GJ inverse of T and S, LU det of V,
// interleaved so the three serial broadcast->rcp->update chains overlap.
// Lane q holds rows q (x0) and q+4 (x1) of each matrix. No pivoting.
__device__ __forceinline__ void elim3(float t0[8], float t1[8],
                                      float s0[8], float s1[8],
                                      float v0[8], float v1[8],
                                      float& ppT, float& ppS, float& ppV,
                                      int q) {
    ppT = 1.f; ppS = 1.f; ppV = 1.f;
#pragma unroll
    for (int k = 0; k < 8; ++k) {
        float Tk[8], Sk[8], Vk[8];
        bcast_row(Tk, t0, t1, k);
        bcast_row(Sk, s0, s1, k);
#pragma unroll
        for (int c = k; c < 8; ++c) {          // V: only cols >= k needed
            float sv = (k < 4) ? v0[c] : v1[c];
            Vk[c] = qb(sv, k & 3);
        }
        float pT = Tk[k], pS = Sk[k], pV = Vk[k];
        ppT *= pT; ppS *= pS; ppV *= pV;
        float iT = frcp(pT), iS = frcp(pS), iV = frcp(pV);
        const bool own0 = (k < 4) && (q == k);
        const bool own1 = (k >= 4) && (q == k - 4);
        float mT0 = -(own0 ? -1.0f : t0[k]) * iT;
        float mT1 = -(own1 ? -1.0f : t1[k]) * iT;
        float mS0 = -(own0 ? -1.0f : s0[k]) * iS;
        float mS1 = -(own1 ? -1.0f : s1[k]) * iS;
        float fV0 = (q > k) ? v0[k] * iV : 0.f;
        float fV1 = (q + 4 > k) ? v1[k] * iV : 0.f;
#pragma unroll
        for (int c = 0; c < 8; ++c) {
            float bT0 = own0 ? 0.0f : t0[c];
            float bT1 = own1 ? 0.0f : t1[c];
            t0[c] = fmaf(mT0, Tk[c], bT0);
            t1[c] = fmaf(mT1, Tk[c], bT1);
            float bS0 = own0 ? 0.0f : s0[c];
            float bS1 = own1 ? 0.0f : s1[c];
            s0[c] = fmaf(mS0, Sk[c], bS0);
            s1[c] = fmaf(mS1, Sk[c], bS1);
        }
        t0[k] = mT0; t1[k] = mT1;
        s0[k] = mS0; s1[k] = mS1;
#pragma unroll
        for (int c = k + 1; c < 8; ++c) {
            v0[c] = fmaf(-fV0, Vk[c], v0[c]);
            v1[c] = fmaf(-fV1, Vk[c], v1[c]);
        }
    }
}

__global__ __launch_bounds__(64) void pairkl_kernel(
    const float* __restrict__ omega, const float* __restrict__ links,
    const float* __restrict__ mu, const float* __restrict__ sigma,
    float* __restrict__ out) {
    __shared__ __align__(16) float sh_x[NN][STR];
    __shared__ __align__(16) float sh_y[NN][STR];
    // sigma stage overlaid on sh_y (15*68+64 = 1084 <= 1216 floats): every
    // sh_s read precedes every sh_y write in the single wave's program order,
    // and sh_s aliases sh_y so the compiler cannot reorder them.
    float* sh_s = &sh_y[0][0];  // layout [item][SSTR]

    const int bid  = blockIdx.x;
    const int g    = (bid & 7) * (NWG / 8) + (bid >> 3);  // XCD-bijective swizzle
    const int lane = threadIdx.x;
    const int item = lane >> 2;
    const int q    = lane & 3;
    const int mb   = (item * GG + g) * 64;

    // ---- Loads: V, omega, sigma to regs; sigma also staged to LDS ----
    float v0[8], v1[8], o0[8], o1[8], s0[8], s1[8], mq[8];
    {
        const float* l0p = links + ((item * 2 + 0) * GG + g) * 64;
        const float* l1p = links + ((item * 2 + 1) * GG + g) * 64;
        float la[8], lb[8];
        ld_row(la, l0p + q * 8);
        ld_row(lb, l1p + q * 8);
#pragma unroll
        for (int c = 0; c < 8; ++c) v0[c] = la[c] + lb[c] - ((c == q) ? 1.f : 0.f);
        ld_row(la, l0p + (q + 4) * 8);
        ld_row(lb, l1p + (q + 4) * 8);
#pragma unroll
        for (int c = 0; c < 8; ++c) v1[c] = la[c] + lb[c] - ((c == q + 4) ? 1.f : 0.f);
    }
    ld_row(o0, omega + mb + q * 8);
    ld_row(o1, omega + mb + (q + 4) * 8);
    ld_row(s0, sigma + mb + q * 8);
    ld_row(s1, sigma + mb + (q + 4) * 8);
    st_row(&sh_s[item * SSTR + q * 8], s0);
    st_row(&sh_s[item * SSTR + (q + 4) * 8], s1);
    ld_row(mq, mu + (item * GG + g) * 8);

    // ---- T = omega @ V ----
    float R0[8], R1[8];
#pragma unroll
    for (int c = 0; c < 8; ++c) { R0[c] = 0.f; R1[c] = 0.f; }
#pragma unroll
    for (int b = 0; b < 8; ++b) {
        float Vb[8]; bcast_row(Vb, v0, v1, b);
#pragma unroll
        for (int c = 0; c < 8; ++c) {
            R0[c] = fmaf(o0[b], Vb[c], R0[c]);
            R1[c] = fmaf(o1[b], Vb[c], R1[c]);
        }
    }

    // ---- Fused eliminations: R=T^{-1}, s=sigma^{-1}, det V ----
    float ppT, ppS, ppV;
    elim3(R0, R1, s0, s1, v0, v1, ppT, ppS, ppV, q);
    float ldT = flogabs(ppT);
    float ld1 = flogabs(ppS);
    float ldV = flogabs(ppV);

    // ---- Fused streams: Z = Winv @ sigma (LDS) || U = siginv @ omega (DPP) ----
    float Z0[8], Z1[8], U0[8], U1[8];
#pragma unroll
    for (int c = 0; c < 8; ++c) { Z0[c] = 0.f; Z1[c] = 0.f; U0[c] = 0.f; U1[c] = 0.f; }
#pragma unroll
    for (int b = 0; b < 8; ++b) {
        float sr[8]; ld_row(sr, &sh_s[item * SSTR + b * 8]);   // original sigma
        float Ob[8]; bcast_row(Ob, o0, o1, b);
#pragma unroll
        for (int c = 0; c < 8; ++c) {
            Z0[c] = fmaf(R0[b], sr[c], Z0[c]);
            Z1[c] = fmaf(R1[b], sr[c], Z1[c]);
            U0[c] = fmaf(s0[b], Ob[c], U0[c]);
            U1[c] = fmaf(s1[b], Ob[c], U1[c]);
        }
    }

    float u_lo = dot8(R0, mq), u_hi = dot8(R1, mq);
    float uf[8];
#pragma unroll
    for (int c = 0; c < 4; ++c) { uf[c] = qb(u_lo, c); uf[c + 4] = qb(u_hi, c); }
    float mql = sel_lo(mq, q), mqh = sel_hi(mq, q);
    float cc  = qsum(dot8(s0, mq) * mql + dot8(s1, mq) * mqh);
    float wf[8];
#pragma unroll
    for (int c = 0; c < 8; ++c) wf[c] = qsum(fmaf(mql, U0[c], mqh * U1[c]));

    // ---- X = Z Winv^T + u u^T  (reuse v regs) ----
#pragma unroll
    for (int c = 0; c < 8; ++c) {
        float Wc[8]; bcast_row(Wc, R0, R1, c);
        v0[c] = fmaf(u_lo, uf[c], dot8(Z0, Wc));
        v1[c] = fmaf(u_hi, uf[c], dot8(Z1, Wc));
    }
    st_row(&sh_x[item][q * 8], v0);
    st_row(&sh_x[item][(q + 4) * 8], v1);

    // ---- P = omega^T U  (omega columns from global, L1-hot; reuse s regs) ----
    float oc0[8], oc1[8];
#pragma unroll
    for (int a = 0; a < 8; ++a) {
        oc0[a] = omega[mb + a * 8 + q];
        oc1[a] = omega[mb + a * 8 + q + 4];
    }
#pragma unroll
    for (int c = 0; c < 8; ++c) { s0[c] = 0.f; s1[c] = 0.f; }
#pragma unroll
    for (int a = 0; a < 8; ++a) {
        float Ua[8]; bcast_row(Ua, U0, U1, a);
#pragma unroll
        for (int c = 0; c < 8; ++c) {
            s0[c] = fmaf(oc0[a], Ua[c], s0[c]);
            s1[c] = fmaf(oc1[a], Ua[c], s1[c]);
        }
    }
    st_row(&sh_y[item][q * 8], s0);   // after this, sh_s region may be clobbered
    st_row(&sh_y[item][(q + 4) * 8], s1);

    if (q == 0) {
        float ldo = ldT - ldV;
        float a_i = 2.f * ldT - ld1;
        float s_j = ld1 - 2.f * ldo + cc - 8.0f;
        *(float4*)&sh_x[item][64] = make_float4(uf[0], uf[1], uf[2], uf[3]);
        *(float4*)&sh_x[item][68] = make_float4(uf[4], uf[5], uf[6], uf[7]);
        *(float4*)&sh_x[item][72] = make_float4(a_i, 1.f, 0.f, 0.f);
        *(float4*)&sh_y[item][64] =
            make_float4(-2.f * wf[0], -2.f * wf[1], -2.f * wf[2], -2.f * wf[3]);
        *(float4*)&sh_y[item][68] =
            make_float4(-2.f * wf[4], -2.f * wf[5], -2.f * wf[6], -2.f * wf[7]);
        *(float4*)&sh_y[item][72] = make_float4(1.f, s_j, 0.f, 0.f);
    }
    // single-wave workgroup: DS ops complete in program order; compiler
    // inserts lgkmcnt for RAW. Fence stops compile-time reordering.
    asm volatile("" ::: "memory");

    // ---- Phase 2: E[i,j] = 0.5 * dot76(x_i, y_j); 2i x 2j per lane ----
    {
        const int i0 = lane >> 3, j0 = lane & 7;
        const int i1 = i0 + 8, j1 = j0 + 8;
        const float4* x0 = (const float4*)&sh_x[i0][0];
        const float4* x1 = (const float4*)&sh_x[i1][0];
        const float4* y0 = (const float4*)&sh_y[j0][0];
        const float4* y1 = (const float4*)&sh_y[j1][0];
        float d00 = 0.f, d01 = 0.f, d10 = 0.f, d11 = 0.f;
#pragma unroll
        for (int k = 0; k < STR / 4; ++k) {
            float4 a0 = x0[k], a1 = x1[k], b0 = y0[k], b1 = y1[k];
            d00 = fmaf(a0.x, b0.x, d00); d00 = fmaf(a0.y, b0.y, d00);
            d00 = fmaf(a0.z, b0.z, d00); d00 = fmaf(a0.w, b0.w, d00);
            d01 = fmaf(a0.x, b1.x, d01); d01 = fmaf(a0.y, b1.y, d01);
            d01 = fmaf(a0.z, b1.z, d01); d01 = fmaf(a0.w, b1.w, d01);
            d10 = fmaf(a1.x, b0.x, d10); d10 = fmaf(a1.y, b0.y, d10);
            d10 = fmaf(a1.z, b0.z, d10); d10 = fmaf(a1.w, b0.w, d10);
            d11 = fmaf(a1.x, b1.x, d11); d11 = fmaf(a1.y, b1.y, d11);
            d11 = fmaf(a1.z, b1.z, d11); d11 = fmaf(a1.w, b1.w, d11);
        }
        const bool dg = (i0 == j0);
        out[(i0 * NN + j0) * GG + g] = dg ? 0.f : 0.5f * d00;
        out[(i0 * NN + j1) * GG + g] = 0.5f * d01;
        out[(i1 * NN + j0) * GG + g] = 0.5f * d10;
        out[(i1 * NN + j1) * GG + g] = dg ? 0.f : 0.5f * d11;
    }
}

extern "C" void kernel_launch(void* const* d_in, const int* in_sizes, int n_in,
                              void* d_out, int out_size, void* d_ws, size_t ws_size,
                              hipStream_t stream) {
    const float* omega = (const float*)d_in[0];
    const float* links = (const float*)d_in[1];
    const float* mu    = (const float*)d_in[2];
    const float* sigma = (const float*)d_in[3];
    float* out = (float*)d_out;
    hipLaunchKernelGGL(pairkl_kernel, dim3(NWG), dim3(64), 0, stream,
                       omega, links, mu, sigma, out);
}